// Round 3
// baseline (275.664 us; speedup 1.0000x reference)
//
#include <hip/hip_runtime.h>

// Problem constants (from reference)
#define Bc 2
#define Vc 5
#define Cc 32
#define Hc 256
#define Wc 320
#define Nc 40000
#define HWc (Hc * Wc)

#define NMAIN ((Bc * Vc * 2 * Nc * 2) / 256)   // 6250 main blocks (bvh,n,cq2)

typedef float v2f __attribute__((ext_vector_type(2)));

__device__ __forceinline__ unsigned bf16_rn(float x) {
    unsigned u = __float_as_uint(x);
    return (u + 0x7fffu + ((u >> 16) & 1u)) >> 16;   // round-to-nearest-even
}

// ---------------------------------------------------------------------------
// Pass 1: transpose + convert: fm (BV,C,HW) f32 -> fmT in HALF-IMAGE layout:
//   (bv*2 + half, HW, 16ch) bf16. Half-pixel = 32 B. (proven R1 version)
// ---------------------------------------------------------------------------
__global__ void __launch_bounds__(256)
transpose_bf16_kernel(const float* __restrict__ fm, unsigned short* __restrict__ fmT)
{
    __shared__ float tile[Cc][65];   // +1 pad: conflict-free both phases
    const int bv  = blockIdx.y;
    const int hw0 = blockIdx.x * 64;
    const int t   = threadIdx.x;

    const int tx = t & 63;
    const int ty = t >> 6;                  // 0..3
    const float* src = fm + (size_t)bv * Cc * HWc + hw0;
    #pragma unroll
    for (int i = 0; i < 8; ++i) {
        int c = ty * 8 + i;
        tile[c][tx] = __builtin_nontemporal_load(&src[(size_t)c * HWc + tx]);
    }
    __syncthreads();

    const int cq = t & 3;                   // chunk: channels cq*8 .. cq*8+7
    const int hw = t >> 2;                  // 0..63
    unsigned r[4];
    #pragma unroll
    for (int j = 0; j < 4; ++j) {
        float a = tile[cq * 8 + 2 * j][hw];
        float b = tile[cq * 8 + 2 * j + 1][hw];
        r[j] = bf16_rn(a) | (bf16_rn(b) << 16);
    }
    const int half = cq >> 1;
    const int sub  = cq & 1;
    uint4* dst = (uint4*)fmT
               + ((size_t)(bv * 2 + half) * HWc + (hw0 + hw)) * 2 + sub;
    *dst = make_uint4(r[0], r[1], r[2], r[3]);
}

// ---------------------------------------------------------------------------
// Pass 2: project + dedup'd 5-sample bilinear (12 gathers common case).
// Samples separate: L/R share center's y axis; T/B share center's x axis.
// Pixel union = rows {y0,y0+1} x {x0-1..x0+2}  +  cols {x0,x0+1} x {y0-1,y0+2}.
// Rare eps-shifted side floors fixed by exact per-lane curvature corrections.
// ---------------------------------------------------------------------------
__device__ __forceinline__ void acc8(float* a, uint4 w, float s) {
    a[0] = fmaf(s, __uint_as_float(w.x << 16),          a[0]);
    a[1] = fmaf(s, __uint_as_float(w.x & 0xffff0000u), a[1]);
    a[2] = fmaf(s, __uint_as_float(w.y << 16),          a[2]);
    a[3] = fmaf(s, __uint_as_float(w.y & 0xffff0000u), a[3]);
    a[4] = fmaf(s, __uint_as_float(w.z << 16),          a[4]);
    a[5] = fmaf(s, __uint_as_float(w.z & 0xffff0000u), a[5]);
    a[6] = fmaf(s, __uint_as_float(w.w << 16),          a[6]);
    a[7] = fmaf(s, __uint_as_float(w.w & 0xffff0000u), a[7]);
}

__global__ void __launch_bounds__(256)
fgf_main(const unsigned short* __restrict__ fmT,
         const float* __restrict__ pts,
         const float* __restrict__ Kmat,
         const float* __restrict__ Emat,
         float* __restrict__ out_feat,
         float* __restrict__ out_grad)
{
    const int v    = blockIdx.x * 256 + (int)threadIdx.x;   // < 1.6M
    const int cq2  = v & 1;                  // 16B chunk within half-pixel
    const int rest = v >> 1;                 // < 800000
    const int n    = rest % Nc;
    const int bvh  = rest / Nc;              // 0..19: (bv, half)
    const int bv   = bvh >> 1;
    const int half = bvh & 1;
    const int b    = bv / Vc;

    // Point (B,3,N)
    const float* p = pts + (size_t)(b * 3) * Nc + n;
    float px = p[0];
    float py = p[Nc];
    float pz = p[2 * Nc];

    // Extrinsics (B,V,3,4), intrinsics (B,V,3,3)
    const float* Ep = Emat + bv * 12;
    const float* Kp = Kmat + bv * 9;
    float x = Ep[0] * px + Ep[1] * py + Ep[2]  * pz + Ep[3];
    float y = Ep[4] * px + Ep[5] * py + Ep[6]  * pz + Ep[7];
    float z = Ep[8] * px + Ep[9] * py + Ep[10] * pz + Ep[11];
    float xz = x / z;
    float yz = y / z;
    float u  = Kp[0] * xz + Kp[1] * yz + Kp[2];
    float vv = Kp[3] * xz + Kp[4] * yz + Kp[5];

    const float sxp = (float)Wc / (float)(Wc - 1);   // pixel-space sample offset
    const float syp = (float)Hc / (float)(Hc - 1);
    float ix = (u  - 0.5f) * sxp - 0.5f;
    float iy = (vv - 0.5f) * syp - 0.5f;

    // ---- center floors / fracs ----
    float x0f = floorf(ix), y0f = floorf(iy);
    float wx = ix - x0f, wy = iy - y0f;
    int x0 = (int)x0f, y0 = (int)y0f;

    // ---- side sample positions (same arithmetic as previous kernel) ----
    float ixL = ix - sxp, ixR = ix + sxp;
    float iyT = iy - syp, iyB = iy + syp;
    float xLf = floorf(ixL), xRf = floorf(ixR);
    float yTf = floorf(iyT), yBf = floorf(iyB);
    // assumed-floor fracs (floor assumed x0-1, x0+1, y0-1, y0+1)
    float wLa = ixL - (x0f - 1.0f);          // in (-eps, 1)
    float wRa = ixR - (x0f + 1.0f);          // in (0, 1+eps)
    float wTa = iyT - (y0f - 1.0f);
    float wBa = iyB - (y0f + 1.0f);
    bool mL = xLf < x0f - 1.5f;              // true floor is x0-2
    bool mR = xRf > x0f + 1.5f;              // true floor is x0+2
    bool mT = yTf < y0f - 1.5f;
    bool mB = yBf > y0f + 1.5f;

    // ---- weights ----
    float cx0 = 1.0f - wx, cx1 = wx;
    float cy0 = 1.0f - wy, cy1 = wy;
    float gw0 = -0.5f * (1.0f - wLa);        // gx weight @ x0-1
    float gw1 = -0.5f * wLa;                 // @ x0
    float gw2 =  0.5f * (1.0f - wRa);        // @ x0+1
    float gw3 =  0.5f * wRa;                 // @ x0+2
    float gym  = -0.5f * (1.0f - wTa);       // gy weight @ row y0-1
    float gyr0 = -0.5f * wTa;                // @ row y0
    float gyr1 =  0.5f * (1.0f - wBa);       // @ row y0+1
    float gyp  =  0.5f * wBa;                // @ row y0+2

    // ---- validity (0/1 floats) ----
    float vxm1 = ((unsigned)(x0 - 1) < (unsigned)Wc) ? 1.0f : 0.0f;
    float vx00 = ((unsigned)(x0    ) < (unsigned)Wc) ? 1.0f : 0.0f;
    float vx01 = ((unsigned)(x0 + 1) < (unsigned)Wc) ? 1.0f : 0.0f;
    float vx02 = ((unsigned)(x0 + 2) < (unsigned)Wc) ? 1.0f : 0.0f;
    float vym1 = ((unsigned)(y0 - 1) < (unsigned)Hc) ? 1.0f : 0.0f;
    float vy00 = ((unsigned)(y0    ) < (unsigned)Hc) ? 1.0f : 0.0f;
    float vy01 = ((unsigned)(y0 + 1) < (unsigned)Hc) ? 1.0f : 0.0f;
    float vy02 = ((unsigned)(y0 + 2) < (unsigned)Hc) ? 1.0f : 0.0f;

    // ---- clamped addresses ----
    const uint4* base4 = (const uint4*)fmT + (size_t)bvh * (HWc * 2) + cq2;
    int cxm1 = min(max(x0 - 1, 0), Wc - 1);
    int cx0b = min(max(x0,     0), Wc - 1);
    int cx1b = min(max(x0 + 1, 0), Wc - 1);
    int cx2b = min(max(x0 + 2, 0), Wc - 1);
    int ry0  = min(max(y0,     0), Hc - 1) * Wc;
    int ry1  = min(max(y0 + 1, 0), Hc - 1) * Wc;
    int rym1 = min(max(y0 - 1, 0), Hc - 1) * Wc;
    int ry2  = min(max(y0 + 2, 0), Hc - 1) * Wc;

    // ---- 12 base gathers ----
    uint4 P00 = base4[(unsigned)(ry0 + cxm1) * 2u];
    uint4 P01 = base4[(unsigned)(ry0 + cx0b) * 2u];
    uint4 P02 = base4[(unsigned)(ry0 + cx1b) * 2u];
    uint4 P03 = base4[(unsigned)(ry0 + cx2b) * 2u];
    uint4 P10 = base4[(unsigned)(ry1 + cxm1) * 2u];
    uint4 P11 = base4[(unsigned)(ry1 + cx0b) * 2u];
    uint4 P12 = base4[(unsigned)(ry1 + cx1b) * 2u];
    uint4 P13 = base4[(unsigned)(ry1 + cx2b) * 2u];
    uint4 Qt0 = base4[(unsigned)(rym1 + cx0b) * 2u];
    uint4 Qt1 = base4[(unsigned)(rym1 + cx1b) * 2u];
    uint4 Qb0 = base4[(unsigned)(ry2 + cx0b) * 2u];
    uint4 Qb1 = base4[(unsigned)(ry2 + cx1b) * 2u];

    float acc[3][8];
    #pragma unroll
    for (int a = 0; a < 3; ++a)
        #pragma unroll
        for (int j = 0; j < 8; ++j) acc[a][j] = 0.0f;
    float* f  = acc[0];
    float* gx = acc[1];
    float* gy = acc[2];

    // row y0
    acc8(f,  P01, cx0 * cy0 * vx00 * vy00);
    acc8(f,  P02, cx1 * cy0 * vx01 * vy00);
    acc8(gx, P00, gw0 * cy0 * vxm1 * vy00);
    acc8(gx, P01, gw1 * cy0 * vx00 * vy00);
    acc8(gx, P02, gw2 * cy0 * vx01 * vy00);
    acc8(gx, P03, gw3 * cy0 * vx02 * vy00);
    acc8(gy, P01, gyr0 * cx0 * vx00 * vy00);
    acc8(gy, P02, gyr0 * cx1 * vx01 * vy00);
    // row y0+1
    acc8(f,  P11, cx0 * cy1 * vx00 * vy01);
    acc8(f,  P12, cx1 * cy1 * vx01 * vy01);
    acc8(gx, P10, gw0 * cy1 * vxm1 * vy01);
    acc8(gx, P11, gw1 * cy1 * vx00 * vy01);
    acc8(gx, P12, gw2 * cy1 * vx01 * vy01);
    acc8(gx, P13, gw3 * cy1 * vx02 * vy01);
    acc8(gy, P11, gyr1 * cx0 * vx00 * vy01);
    acc8(gy, P12, gyr1 * cx1 * vx01 * vy01);
    // rows y0-1 / y0+2 (gy only)
    acc8(gy, Qt0, gym * cx0 * vx00 * vym1);
    acc8(gy, Qt1, gym * cx1 * vx01 * vym1);
    acc8(gy, Qb0, gyp * cx0 * vx00 * vy02);
    acc8(gy, Qb1, gyp * cx1 * vx01 * vy02);

    // ---- exact corrections for eps-shifted side floors (rare, per-lane) ----
    if (mL) {   // L sample真 floor = x0-2: gx += 0.5*wLa*(V(x0-2) - 2V(x0-1) + V(x0))*cy_j
        int cxm2 = min(max(x0 - 2, 0), Wc - 1);
        uint4 M0 = base4[(unsigned)(ry0 + cxm2) * 2u];
        uint4 M1 = base4[(unsigned)(ry1 + cxm2) * 2u];
        float vxm2 = ((unsigned)(x0 - 2) < (unsigned)Wc) ? 1.0f : 0.0f;
        float s = 0.5f * wLa;
        acc8(gx, M0,   s * cy0 * vxm2 * vy00);
        acc8(gx, P00, -2.0f * s * cy0 * vxm1 * vy00);
        acc8(gx, P01,  s * cy0 * vx00 * vy00);
        acc8(gx, M1,   s * cy1 * vxm2 * vy01);
        acc8(gx, P10, -2.0f * s * cy1 * vxm1 * vy01);
        acc8(gx, P11,  s * cy1 * vx00 * vy01);
    }
    if (mR) {   // R true floor = x0+2: gx += 0.5*(wRa-1)*(V(x0+1) - 2V(x0+2) + V(x0+3))*cy_j
        int cx3 = min(max(x0 + 3, 0), Wc - 1);
        uint4 M0 = base4[(unsigned)(ry0 + cx3) * 2u];
        uint4 M1 = base4[(unsigned)(ry1 + cx3) * 2u];
        float vx03 = ((unsigned)(x0 + 3) < (unsigned)Wc) ? 1.0f : 0.0f;
        float e = 0.5f * (wRa - 1.0f);
        acc8(gx, P02,  e * cy0 * vx01 * vy00);
        acc8(gx, P03, -2.0f * e * cy0 * vx02 * vy00);
        acc8(gx, M0,   e * cy0 * vx03 * vy00);
        acc8(gx, P12,  e * cy1 * vx01 * vy01);
        acc8(gx, P13, -2.0f * e * cy1 * vx02 * vy01);
        acc8(gx, M1,   e * cy1 * vx03 * vy01);
    }
    if (mT) {   // T true floor = y0-2: gy += 0.5*wTa*(V(y0-2) - 2V(y0-1) + V(y0))*cx_i
        int rym2 = min(max(y0 - 2, 0), Hc - 1) * Wc;
        uint4 M0 = base4[(unsigned)(rym2 + cx0b) * 2u];
        uint4 M1 = base4[(unsigned)(rym2 + cx1b) * 2u];
        float vym2 = ((unsigned)(y0 - 2) < (unsigned)Hc) ? 1.0f : 0.0f;
        float s = 0.5f * wTa;
        acc8(gy, M0,   s * cx0 * vx00 * vym2);
        acc8(gy, Qt0, -2.0f * s * cx0 * vx00 * vym1);
        acc8(gy, P01,  s * cx0 * vx00 * vy00);
        acc8(gy, M1,   s * cx1 * vx01 * vym2);
        acc8(gy, Qt1, -2.0f * s * cx1 * vx01 * vym1);
        acc8(gy, P02,  s * cx1 * vx01 * vy00);
    }
    if (mB) {   // B true floor = y0+2: gy += 0.5*(wBa-1)*(V(y0+1) - 2V(y0+2) + V(y0+3))*cx_i
        int ry3 = min(max(y0 + 3, 0), Hc - 1) * Wc;
        uint4 M0 = base4[(unsigned)(ry3 + cx0b) * 2u];
        uint4 M1 = base4[(unsigned)(ry3 + cx1b) * 2u];
        float vy03 = ((unsigned)(y0 + 3) < (unsigned)Hc) ? 1.0f : 0.0f;
        float e = 0.5f * (wBa - 1.0f);
        acc8(gy, P11,  e * cx0 * vx00 * vy01);
        acc8(gy, Qb0, -2.0f * e * cx0 * vx00 * vy02);
        acc8(gy, M0,   e * cx0 * vx00 * vy03);
        acc8(gy, P12,  e * cx1 * vx01 * vy01);
        acc8(gy, Qb1, -2.0f * e * cx1 * vx01 * vy02);
        acc8(gy, M1,   e * cx1 * vx01 * vy03);
    }

    // Outputs: feat (BV,C,N) f32, grad (BV,C,N,2) f32 — nontemporal
    const int cbase = half * 16 + cq2 * 8;
    size_t obase = (size_t)bv * Cc * Nc + n;
    v2f* gp = (v2f*)out_grad;
    #pragma unroll
    for (int j = 0; j < 8; ++j) {
        int c = cbase + j;
        __builtin_nontemporal_store(acc[0][j], &out_feat[obase + (size_t)c * Nc]);
        v2f g = {acc[1][j], acc[2][j]};
        __builtin_nontemporal_store(g, &gp[obase + (size_t)c * Nc]);
    }
}

// ---------------------------------------------------------------------------
// Fallback (round-1 style, NCHW direct) if ws is too small.
// ---------------------------------------------------------------------------
__device__ __forceinline__ float fetch_px(const float* __restrict__ fm, int x, int y) {
    if (x < 0 || x >= Wc || y < 0 || y >= Hc) return 0.0f;
    return fm[y * Wc + x];
}
__device__ __forceinline__ float bilin(const float* __restrict__ fm, float ix, float iy) {
    float x0f = floorf(ix), y0f = floorf(iy);
    float wx = ix - x0f, wy = iy - y0f;
    int x0 = (int)x0f, y0 = (int)y0f;
    float v00 = fetch_px(fm, x0, y0);
    float v10 = fetch_px(fm, x0 + 1, y0);
    float v01 = fetch_px(fm, x0, y0 + 1);
    float v11 = fetch_px(fm, x0 + 1, y0 + 1);
    return (v00 * (1.0f - wx) + v10 * wx) * (1.0f - wy)
         + (v01 * (1.0f - wx) + v11 * wx) * wy;
}
__global__ void __launch_bounds__(256)
fgf_fallback(const float* __restrict__ fm,
             const float* __restrict__ pts,
             const float* __restrict__ Kmat,
             const float* __restrict__ Emat,
             float* __restrict__ out_feat,
             float* __restrict__ out_grad)
{
    int idx = blockIdx.x * 256 + threadIdx.x;
    const int total = Bc * Vc * Cc * Nc;
    if (idx >= total) return;
    int n = idx % Nc;
    int tcb = idx / Nc;
    int c = tcb % Cc;
    int bv = tcb / Cc;
    int b = bv / Vc;
    const float* p = pts + (size_t)(b * 3) * Nc + n;
    float px = p[0], py = p[Nc], pz = p[2 * Nc];
    const float* Ep = Emat + bv * 12;
    const float* Kp = Kmat + bv * 9;
    float x = Ep[0] * px + Ep[1] * py + Ep[2] * pz + Ep[3];
    float y = Ep[4] * px + Ep[5] * py + Ep[6] * pz + Ep[7];
    float z = Ep[8] * px + Ep[9] * py + Ep[10] * pz + Ep[11];
    float xz = x / z, yz = y / z;
    float u = Kp[0] * xz + Kp[1] * yz + Kp[2];
    float v = Kp[3] * xz + Kp[4] * yz + Kp[5];
    const float sxp = (float)Wc / (float)(Wc - 1);
    const float syp = (float)Hc / (float)(Hc - 1);
    float ix = (u - 0.5f) * sxp - 0.5f;
    float iy = (v - 0.5f) * syp - 0.5f;
    const float* f = fm + (size_t)(bv * Cc + c) * HWc;
    float feat = bilin(f, ix, iy);
    float fl = bilin(f, ix - sxp, iy);
    float fr = bilin(f, ix + sxp, iy);
    float ft = bilin(f, ix, iy - syp);
    float fb = bilin(f, ix, iy + syp);
    size_t o = (size_t)(bv * Cc + c) * Nc + n;
    out_feat[o] = feat;
    ((float2*)out_grad)[o] = make_float2(0.5f * (fr - fl), 0.5f * (fb - ft));
}

extern "C" void kernel_launch(void* const* d_in, const int* in_sizes, int n_in,
                              void* d_out, int out_size, void* d_ws, size_t ws_size,
                              hipStream_t stream) {
    const float* fm  = (const float*)d_in[0];  // (B,V,C,H,W)
    const float* pts = (const float*)d_in[1];  // (B,3,N)
    const float* K   = (const float*)d_in[2];  // (B,V,3,3)
    const float* E   = (const float*)d_in[3];  // (B,V,3,4)

    float* out_feat = (float*)d_out;                               // (B,V,C,N)
    float* out_grad = (float*)d_out + (size_t)Bc * Vc * Cc * Nc;   // (B,V,C,N,2)

    const size_t fmT_bytes = (size_t)Bc * Vc * Cc * HWc * sizeof(unsigned short); // 52,428,800

    if (ws_size >= fmT_bytes) {
        unsigned short* fmT = (unsigned short*)d_ws;
        dim3 tgrid(HWc / 64, Bc * Vc);
        transpose_bf16_kernel<<<tgrid, 256, 0, stream>>>(fm, fmT);
        fgf_main<<<NMAIN, 256, 0, stream>>>(fmT, pts, K, E, out_feat, out_grad);
    } else {
        const int total = Bc * Vc * Cc * Nc;
        fgf_fallback<<<(total + 255) / 256, 256, 0, stream>>>(fm, pts, K, E, out_feat, out_grad);
    }
}

// Round 5
// 274.916 us; speedup vs baseline: 1.0027x; 1.0027x over previous
//
#include <hip/hip_runtime.h>

// Problem constants (from reference)
#define Bc 2
#define Vc 5
#define Cc 32
#define Hc 256
#define Wc 320
#define Nc 40000
#define HWc (Hc * Wc)

#define NMAIN ((Bc * Vc * 2 * Nc * 2) / 256)   // 6250 main blocks (bvh,n,cq2)
#define TPX 256                                 // pixels per transpose tile

typedef float v2f __attribute__((ext_vector_type(2)));
typedef float v4f __attribute__((ext_vector_type(4)));

__device__ __forceinline__ unsigned bf16_rn(float x) {
    unsigned u = __float_as_uint(x);
    return (u + 0x7fffu + ((u >> 16) & 1u)) >> 16;   // round-to-nearest-even
}

// ---------------------------------------------------------------------------
// Pass 1: transpose + convert: fm (BV,C,HW) f32 -> fmT in HALF-IMAGE layout:
//   (bv*2 + half, HW, 16ch) bf16. Half-pixel = 32 B.
// R5: float4 global loads (16 B/lane, 1 KB/wave-instruction) via ext_vector
// (HIP_vector_type is rejected by __builtin_nontemporal_load).
// Tile: 256 px x 32 ch. LDS stride 258: pack-phase column reads are 2-way
// bank aliased (free per m136); 8 B alignment for the v2f LDS writes.
// ---------------------------------------------------------------------------
__global__ void __launch_bounds__(256)
transpose_bf16_kernel(const float* __restrict__ fm, unsigned short* __restrict__ fmT)
{
    __shared__ float tile[Cc][258];
    const int bv  = blockIdx.y;
    const int hw0 = blockIdx.x * TPX;
    const int t   = threadIdx.x;
    const int w   = t >> 6;                 // wave 0..3
    const int l   = t & 63;                 // lane

    const float* src = fm + (size_t)bv * Cc * HWc + hw0;
    #pragma unroll
    for (int i = 0; i < 8; ++i) {
        const int c = w * 8 + i;            // wave w covers channels 8w..8w+7
        const v4f v4 = __builtin_nontemporal_load(
            (const v4f*)&src[(size_t)c * HWc + 4 * l]);
        v2f lo = {v4.x, v4.y};
        v2f hi = {v4.z, v4.w};
        *(v2f*)&tile[c][4 * l]     = lo;
        *(v2f*)&tile[c][4 * l + 2] = hi;
    }
    __syncthreads();

    const int cq = t & 3;                   // chunk: channels cq*8 .. cq*8+7
    const int half = cq >> 1;
    const int sub  = cq & 1;
    #pragma unroll
    for (int k = 0; k < 4; ++k) {
        const int px = (t >> 2) + 64 * k;
        unsigned r[4];
        #pragma unroll
        for (int j = 0; j < 4; ++j) {
            float a = tile[cq * 8 + 2 * j][px];
            float b = tile[cq * 8 + 2 * j + 1][px];
            r[j] = bf16_rn(a) | (bf16_rn(b) << 16);
        }
        uint4* dst = (uint4*)fmT
                   + ((size_t)(bv * 2 + half) * HWc + (hw0 + px)) * 2 + sub;
        *dst = make_uint4(r[0], r[1], r[2], r[3]);
    }
}

// ---------------------------------------------------------------------------
// Pass 2: project + dedup'd 5-sample bilinear (12 gathers common case).
// (unchanged from R3 — verified passing, absmax 0.03125)
// ---------------------------------------------------------------------------
__device__ __forceinline__ void acc8(float* a, uint4 w, float s) {
    a[0] = fmaf(s, __uint_as_float(w.x << 16),          a[0]);
    a[1] = fmaf(s, __uint_as_float(w.x & 0xffff0000u), a[1]);
    a[2] = fmaf(s, __uint_as_float(w.y << 16),          a[2]);
    a[3] = fmaf(s, __uint_as_float(w.y & 0xffff0000u), a[3]);
    a[4] = fmaf(s, __uint_as_float(w.z << 16),          a[4]);
    a[5] = fmaf(s, __uint_as_float(w.z & 0xffff0000u), a[5]);
    a[6] = fmaf(s, __uint_as_float(w.w << 16),          a[6]);
    a[7] = fmaf(s, __uint_as_float(w.w & 0xffff0000u), a[7]);
}

__global__ void __launch_bounds__(256)
fgf_main(const unsigned short* __restrict__ fmT,
         const float* __restrict__ pts,
         const float* __restrict__ Kmat,
         const float* __restrict__ Emat,
         float* __restrict__ out_feat,
         float* __restrict__ out_grad)
{
    const int v    = blockIdx.x * 256 + (int)threadIdx.x;   // < 1.6M
    const int cq2  = v & 1;                  // 16B chunk within half-pixel
    const int rest = v >> 1;                 // < 800000
    const int n    = rest % Nc;
    const int bvh  = rest / Nc;              // 0..19: (bv, half)
    const int bv   = bvh >> 1;
    const int half = bvh & 1;
    const int b    = bv / Vc;

    // Point (B,3,N)
    const float* p = pts + (size_t)(b * 3) * Nc + n;
    float px = p[0];
    float py = p[Nc];
    float pz = p[2 * Nc];

    // Extrinsics (B,V,3,4), intrinsics (B,V,3,3)
    const float* Ep = Emat + bv * 12;
    const float* Kp = Kmat + bv * 9;
    float x = Ep[0] * px + Ep[1] * py + Ep[2]  * pz + Ep[3];
    float y = Ep[4] * px + Ep[5] * py + Ep[6]  * pz + Ep[7];
    float z = Ep[8] * px + Ep[9] * py + Ep[10] * pz + Ep[11];
    float xz = x / z;
    float yz = y / z;
    float u  = Kp[0] * xz + Kp[1] * yz + Kp[2];
    float vv = Kp[3] * xz + Kp[4] * yz + Kp[5];

    const float sxp = (float)Wc / (float)(Wc - 1);   // pixel-space sample offset
    const float syp = (float)Hc / (float)(Hc - 1);
    float ix = (u  - 0.5f) * sxp - 0.5f;
    float iy = (vv - 0.5f) * syp - 0.5f;

    // ---- center floors / fracs ----
    float x0f = floorf(ix), y0f = floorf(iy);
    float wx = ix - x0f, wy = iy - y0f;
    int x0 = (int)x0f, y0 = (int)y0f;

    // ---- side sample positions ----
    float ixL = ix - sxp, ixR = ix + sxp;
    float iyT = iy - syp, iyB = iy + syp;
    float xLf = floorf(ixL), xRf = floorf(ixR);
    float yTf = floorf(iyT), yBf = floorf(iyB);
    float wLa = ixL - (x0f - 1.0f);          // assumed-floor fracs
    float wRa = ixR - (x0f + 1.0f);
    float wTa = iyT - (y0f - 1.0f);
    float wBa = iyB - (y0f + 1.0f);
    bool mL = xLf < x0f - 1.5f;              // true floor is x0-2
    bool mR = xRf > x0f + 1.5f;
    bool mT = yTf < y0f - 1.5f;
    bool mB = yBf > y0f + 1.5f;

    // ---- weights ----
    float cx0 = 1.0f - wx, cx1 = wx;
    float cy0 = 1.0f - wy, cy1 = wy;
    float gw0 = -0.5f * (1.0f - wLa);        // gx weight @ x0-1
    float gw1 = -0.5f * wLa;                 // @ x0
    float gw2 =  0.5f * (1.0f - wRa);        // @ x0+1
    float gw3 =  0.5f * wRa;                 // @ x0+2
    float gym  = -0.5f * (1.0f - wTa);       // gy weight @ row y0-1
    float gyr0 = -0.5f * wTa;                // @ row y0
    float gyr1 =  0.5f * (1.0f - wBa);       // @ row y0+1
    float gyp  =  0.5f * wBa;                // @ row y0+2

    // ---- validity (0/1 floats) ----
    float vxm1 = ((unsigned)(x0 - 1) < (unsigned)Wc) ? 1.0f : 0.0f;
    float vx00 = ((unsigned)(x0    ) < (unsigned)Wc) ? 1.0f : 0.0f;
    float vx01 = ((unsigned)(x0 + 1) < (unsigned)Wc) ? 1.0f : 0.0f;
    float vx02 = ((unsigned)(x0 + 2) < (unsigned)Wc) ? 1.0f : 0.0f;
    float vym1 = ((unsigned)(y0 - 1) < (unsigned)Hc) ? 1.0f : 0.0f;
    float vy00 = ((unsigned)(y0    ) < (unsigned)Hc) ? 1.0f : 0.0f;
    float vy01 = ((unsigned)(y0 + 1) < (unsigned)Hc) ? 1.0f : 0.0f;
    float vy02 = ((unsigned)(y0 + 2) < (unsigned)Hc) ? 1.0f : 0.0f;

    // ---- clamped addresses ----
    const uint4* base4 = (const uint4*)fmT + (size_t)bvh * (HWc * 2) + cq2;
    int cxm1 = min(max(x0 - 1, 0), Wc - 1);
    int cx0b = min(max(x0,     0), Wc - 1);
    int cx1b = min(max(x0 + 1, 0), Wc - 1);
    int cx2b = min(max(x0 + 2, 0), Wc - 1);
    int ry0  = min(max(y0,     0), Hc - 1) * Wc;
    int ry1  = min(max(y0 + 1, 0), Hc - 1) * Wc;
    int rym1 = min(max(y0 - 1, 0), Hc - 1) * Wc;
    int ry2  = min(max(y0 + 2, 0), Hc - 1) * Wc;

    // ---- 12 base gathers ----
    uint4 P00 = base4[(unsigned)(ry0 + cxm1) * 2u];
    uint4 P01 = base4[(unsigned)(ry0 + cx0b) * 2u];
    uint4 P02 = base4[(unsigned)(ry0 + cx1b) * 2u];
    uint4 P03 = base4[(unsigned)(ry0 + cx2b) * 2u];
    uint4 P10 = base4[(unsigned)(ry1 + cxm1) * 2u];
    uint4 P11 = base4[(unsigned)(ry1 + cx0b) * 2u];
    uint4 P12 = base4[(unsigned)(ry1 + cx1b) * 2u];
    uint4 P13 = base4[(unsigned)(ry1 + cx2b) * 2u];
    uint4 Qt0 = base4[(unsigned)(rym1 + cx0b) * 2u];
    uint4 Qt1 = base4[(unsigned)(rym1 + cx1b) * 2u];
    uint4 Qb0 = base4[(unsigned)(ry2 + cx0b) * 2u];
    uint4 Qb1 = base4[(unsigned)(ry2 + cx1b) * 2u];

    float acc[3][8];
    #pragma unroll
    for (int a = 0; a < 3; ++a)
        #pragma unroll
        for (int j = 0; j < 8; ++j) acc[a][j] = 0.0f;
    float* f  = acc[0];
    float* gx = acc[1];
    float* gy = acc[2];

    // row y0
    acc8(f,  P01, cx0 * cy0 * vx00 * vy00);
    acc8(f,  P02, cx1 * cy0 * vx01 * vy00);
    acc8(gx, P00, gw0 * cy0 * vxm1 * vy00);
    acc8(gx, P01, gw1 * cy0 * vx00 * vy00);
    acc8(gx, P02, gw2 * cy0 * vx01 * vy00);
    acc8(gx, P03, gw3 * cy0 * vx02 * vy00);
    acc8(gy, P01, gyr0 * cx0 * vx00 * vy00);
    acc8(gy, P02, gyr0 * cx1 * vx01 * vy00);
    // row y0+1
    acc8(f,  P11, cx0 * cy1 * vx00 * vy01);
    acc8(f,  P12, cx1 * cy1 * vx01 * vy01);
    acc8(gx, P10, gw0 * cy1 * vxm1 * vy01);
    acc8(gx, P11, gw1 * cy1 * vx00 * vy01);
    acc8(gx, P12, gw2 * cy1 * vx01 * vy01);
    acc8(gx, P13, gw3 * cy1 * vx02 * vy01);
    acc8(gy, P11, gyr1 * cx0 * vx00 * vy01);
    acc8(gy, P12, gyr1 * cx1 * vx01 * vy01);
    // rows y0-1 / y0+2 (gy only)
    acc8(gy, Qt0, gym * cx0 * vx00 * vym1);
    acc8(gy, Qt1, gym * cx1 * vx01 * vym1);
    acc8(gy, Qb0, gyp * cx0 * vx00 * vy02);
    acc8(gy, Qb1, gyp * cx1 * vx01 * vy02);

    // ---- exact corrections for eps-shifted side floors (rare, per-lane) ----
    if (mL) {
        int cxm2 = min(max(x0 - 2, 0), Wc - 1);
        uint4 M0 = base4[(unsigned)(ry0 + cxm2) * 2u];
        uint4 M1 = base4[(unsigned)(ry1 + cxm2) * 2u];
        float vxm2 = ((unsigned)(x0 - 2) < (unsigned)Wc) ? 1.0f : 0.0f;
        float s = 0.5f * wLa;
        acc8(gx, M0,   s * cy0 * vxm2 * vy00);
        acc8(gx, P00, -2.0f * s * cy0 * vxm1 * vy00);
        acc8(gx, P01,  s * cy0 * vx00 * vy00);
        acc8(gx, M1,   s * cy1 * vxm2 * vy01);
        acc8(gx, P10, -2.0f * s * cy1 * vxm1 * vy01);
        acc8(gx, P11,  s * cy1 * vx00 * vy01);
    }
    if (mR) {
        int cx3 = min(max(x0 + 3, 0), Wc - 1);
        uint4 M0 = base4[(unsigned)(ry0 + cx3) * 2u];
        uint4 M1 = base4[(unsigned)(ry1 + cx3) * 2u];
        float vx03 = ((unsigned)(x0 + 3) < (unsigned)Wc) ? 1.0f : 0.0f;
        float e = 0.5f * (wRa - 1.0f);
        acc8(gx, P02,  e * cy0 * vx01 * vy00);
        acc8(gx, P03, -2.0f * e * cy0 * vx02 * vy00);
        acc8(gx, M0,   e * cy0 * vx03 * vy00);
        acc8(gx, P12,  e * cy1 * vx01 * vy01);
        acc8(gx, P13, -2.0f * e * cy1 * vx02 * vy01);
        acc8(gx, M1,   e * cy1 * vx03 * vy01);
    }
    if (mT) {
        int rym2 = min(max(y0 - 2, 0), Hc - 1) * Wc;
        uint4 M0 = base4[(unsigned)(rym2 + cx0b) * 2u];
        uint4 M1 = base4[(unsigned)(rym2 + cx1b) * 2u];
        float vym2 = ((unsigned)(y0 - 2) < (unsigned)Hc) ? 1.0f : 0.0f;
        float s = 0.5f * wTa;
        acc8(gy, M0,   s * cx0 * vx00 * vym2);
        acc8(gy, Qt0, -2.0f * s * cx0 * vx00 * vym1);
        acc8(gy, P01,  s * cx0 * vx00 * vy00);
        acc8(gy, M1,   s * cx1 * vx01 * vym2);
        acc8(gy, Qt1, -2.0f * s * cx1 * vx01 * vym1);
        acc8(gy, P02,  s * cx1 * vx01 * vy00);
    }
    if (mB) {
        int ry3 = min(max(y0 + 3, 0), Hc - 1) * Wc;
        uint4 M0 = base4[(unsigned)(ry3 + cx0b) * 2u];
        uint4 M1 = base4[(unsigned)(ry3 + cx1b) * 2u];
        float vy03 = ((unsigned)(y0 + 3) < (unsigned)Hc) ? 1.0f : 0.0f;
        float e = 0.5f * (wBa - 1.0f);
        acc8(gy, P11,  e * cx0 * vx00 * vy01);
        acc8(gy, Qb0, -2.0f * e * cx0 * vx00 * vy02);
        acc8(gy, M0,   e * cx0 * vx00 * vy03);
        acc8(gy, P12,  e * cx1 * vx01 * vy01);
        acc8(gy, Qb1, -2.0f * e * cx1 * vx01 * vy02);
        acc8(gy, M1,   e * cx1 * vx01 * vy03);
    }

    // Outputs: feat (BV,C,N) f32, grad (BV,C,N,2) f32 — nontemporal
    const int cbase = half * 16 + cq2 * 8;
    size_t obase = (size_t)bv * Cc * Nc + n;
    v2f* gp = (v2f*)out_grad;
    #pragma unroll
    for (int j = 0; j < 8; ++j) {
        int c = cbase + j;
        __builtin_nontemporal_store(acc[0][j], &out_feat[obase + (size_t)c * Nc]);
        v2f g = {acc[1][j], acc[2][j]};
        __builtin_nontemporal_store(g, &gp[obase + (size_t)c * Nc]);
    }
}

// ---------------------------------------------------------------------------
// Fallback (round-1 style, NCHW direct) if ws is too small.
// ---------------------------------------------------------------------------
__device__ __forceinline__ float fetch_px(const float* __restrict__ fm, int x, int y) {
    if (x < 0 || x >= Wc || y < 0 || y >= Hc) return 0.0f;
    return fm[y * Wc + x];
}
__device__ __forceinline__ float bilin(const float* __restrict__ fm, float ix, float iy) {
    float x0f = floorf(ix), y0f = floorf(iy);
    float wx = ix - x0f, wy = iy - y0f;
    int x0 = (int)x0f, y0 = (int)y0f;
    float v00 = fetch_px(fm, x0, y0);
    float v10 = fetch_px(fm, x0 + 1, y0);
    float v01 = fetch_px(fm, x0, y0 + 1);
    float v11 = fetch_px(fm, x0 + 1, y0 + 1);
    return (v00 * (1.0f - wx) + v10 * wx) * (1.0f - wy)
         + (v01 * (1.0f - wx) + v11 * wx) * wy;
}
__global__ void __launch_bounds__(256)
fgf_fallback(const float* __restrict__ fm,
             const float* __restrict__ pts,
             const float* __restrict__ Kmat,
             const float* __restrict__ Emat,
             float* __restrict__ out_feat,
             float* __restrict__ out_grad)
{
    int idx = blockIdx.x * 256 + threadIdx.x;
    const int total = Bc * Vc * Cc * Nc;
    if (idx >= total) return;
    int n = idx % Nc;
    int tcb = idx / Nc;
    int c = tcb % Cc;
    int bv = tcb / Cc;
    int b = bv / Vc;
    const float* p = pts + (size_t)(b * 3) * Nc + n;
    float px = p[0], py = p[Nc], pz = p[2 * Nc];
    const float* Ep = Emat + bv * 12;
    const float* Kp = Kmat + bv * 9;
    float x = Ep[0] * px + Ep[1] * py + Ep[2] * pz + Ep[3];
    float y = Ep[4] * px + Ep[5] * py + Ep[6] * pz + Ep[7];
    float z = Ep[8] * px + Ep[9] * py + Ep[10] * pz + Ep[11];
    float xz = x / z, yz = y / z;
    float u = Kp[0] * xz + Kp[1] * yz + Kp[2];
    float v = Kp[3] * xz + Kp[4] * yz + Kp[5];
    const float sxp = (float)Wc / (float)(Wc - 1);
    const float syp = (float)Hc / (float)(Hc - 1);
    float ix = (u - 0.5f) * sxp - 0.5f;
    float iy = (v - 0.5f) * syp - 0.5f;
    const float* f = fm + (size_t)(bv * Cc + c) * HWc;
    float feat = bilin(f, ix, iy);
    float fl = bilin(f, ix - sxp, iy);
    float fr = bilin(f, ix + sxp, iy);
    float ft = bilin(f, ix, iy - syp);
    float fb = bilin(f, ix, iy + syp);
    size_t o = (size_t)(bv * Cc + c) * Nc + n;
    out_feat[o] = feat;
    ((float2*)out_grad)[o] = make_float2(0.5f * (fr - fl), 0.5f * (fb - ft));
}

extern "C" void kernel_launch(void* const* d_in, const int* in_sizes, int n_in,
                              void* d_out, int out_size, void* d_ws, size_t ws_size,
                              hipStream_t stream) {
    const float* fm  = (const float*)d_in[0];  // (B,V,C,H,W)
    const float* pts = (const float*)d_in[1];  // (B,3,N)
    const float* K   = (const float*)d_in[2];  // (B,V,3,3)
    const float* E   = (const float*)d_in[3];  // (B,V,3,4)

    float* out_feat = (float*)d_out;                               // (B,V,C,N)
    float* out_grad = (float*)d_out + (size_t)Bc * Vc * Cc * Nc;   // (B,V,C,N,2)

    const size_t fmT_bytes = (size_t)Bc * Vc * Cc * HWc * sizeof(unsigned short); // 52,428,800

    if (ws_size >= fmT_bytes) {
        unsigned short* fmT = (unsigned short*)d_ws;
        dim3 tgrid(HWc / TPX, Bc * Vc);
        transpose_bf16_kernel<<<tgrid, 256, 0, stream>>>(fm, fmT);
        fgf_main<<<NMAIN, 256, 0, stream>>>(fmT, pts, K, E, out_feat, out_grad);
    } else {
        const int total = Bc * Vc * Cc * Nc;
        fgf_fallback<<<(total + 255) / 256, 256, 0, stream>>>(fm, pts, K, E, out_feat, out_grad);
    }
}